// Round 1
// baseline (536.678 us; speedup 1.0000x reference)
//
#include <hip/hip_runtime.h>
#include <hip/hip_bf16.h>

#define BATCH 32
#define S_LEN 4095
#define SEQ   4096
#define E_DIM 1024
#define NH    16
#define HD    64
#define CHUNK 128
#define NCHUNK (SEQ / CHUNK)   // 32

// -------- kernel 0: last valid index per batch --------
__global__ __launch_bounds__(256) void last_kernel(const int* __restrict__ mask,
                                                   int* __restrict__ lastbuf) {
    int b = blockIdx.x;
    int t = threadIdx.x;
    int best = -1;
    for (int s = t; s < SEQ; s += 256)
        if (mask[b * SEQ + s] != 0) best = max(best, s);
    __shared__ int red[256];
    red[t] = best;
    __syncthreads();
    for (int o = 128; o > 0; o >>= 1) {
        if (t < o) red[t] = max(red[t], red[t + o]);
        __syncthreads();
    }
    if (t == 0) lastbuf[b] = (red[0] < 0) ? (SEQ - 1) : red[0];
}

// -------- kernel 1: qkv = h @ c_attn_w + c_attn_b  (32 x 3072) --------
__global__ __launch_bounds__(256) void qkv_kernel(const float* __restrict__ hs,
                                                  const float* __restrict__ W,
                                                  const float* __restrict__ bias,
                                                  float* __restrict__ qkv) {
    int b = blockIdx.y;
    int j = blockIdx.x * 256 + threadIdx.x;
    __shared__ float h[E_DIM];
    for (int i = threadIdx.x; i < E_DIM; i += 256) h[i] = hs[b * E_DIM + i];
    __syncthreads();
    float acc = bias[j];
    for (int i = 0; i < E_DIM; ++i) acc = fmaf(h[i], W[(size_t)i * 3072 + j], acc);
    qkv[b * 3072 + j] = acc;
}

// -------- kernel 2: fused cache-append + flash-decode partials --------
__global__ __launch_bounds__(256) void attn_partial_kernel(
    const float* __restrict__ kcache, const float* __restrict__ vcache,
    const int* __restrict__ mask, const float* __restrict__ bias,
    const float* __restrict__ qkv, const int* __restrict__ lastbuf,
    float* __restrict__ newk, float* __restrict__ newv,
    float* __restrict__ pm, float* __restrict__ pl, float* __restrict__ pctx) {
    const int b = blockIdx.y;
    const int chunk = blockIdx.x;
    const int t = threadIdx.x;
    const int wave = t >> 6;
    const int lane = t & 63;
    const int head = wave * 4 + (lane >> 4);
    const int lig = lane & 15;            // lane within 16-lane head group
    const int col = head * HD + lig * 4;  // column in E
    const int last = lastbuf[b];

    const float4 q4 = *(const float4*)(qkv + b * 3072 + col);
    const float4 kn4 = *(const float4*)(qkv + b * 3072 + 1024 + col);
    const float4 vn4 = *(const float4*)(qkv + b * 3072 + 2048 + col);

    const float* kb = kcache + (size_t)b * S_LEN * E_DIM;
    const float* vb = vcache + (size_t)b * S_LEN * E_DIM;
    float* nkb = newk + (size_t)b * SEQ * E_DIM;
    float* nvb = newv + (size_t)b * SEQ * E_DIM;
    const int* mb = mask + b * SEQ;

    float m = -3.0e38f, l = 0.f;
    float4 acc = make_float4(0.f, 0.f, 0.f, 0.f);

    const int s0 = chunk * CHUNK;
    for (int r = 0; r < CHUNK; ++r) {
        const int s = s0 + r;
        float4 kk, vv;
        if (s == last) {
            kk = kn4; vv = vn4;
        } else if (s < S_LEN) {
            kk = *(const float4*)(kb + (size_t)s * E_DIM + col);
            vv = *(const float4*)(vb + (size_t)s * E_DIM + col);
        } else {
            kk = make_float4(0.f, 0.f, 0.f, 0.f);
            vv = kk;
        }
        *(float4*)(nkb + (size_t)s * E_DIM + col) = kk;
        *(float4*)(nvb + (size_t)s * E_DIM + col) = vv;

        float p = kk.x * q4.x + kk.y * q4.y + kk.z * q4.z + kk.w * q4.w;
        p += __shfl_xor(p, 1);
        p += __shfl_xor(p, 2);
        p += __shfl_xor(p, 4);
        p += __shfl_xor(p, 8);
        float score = p * 0.125f + bias[s];
        if (mb[s] == 0) score = -1.0e9f;

        const float mnew = fmaxf(m, score);
        const float sc = __expf(m - mnew);
        const float w = __expf(score - mnew);
        l = l * sc + w;
        acc.x = acc.x * sc + w * vv.x;
        acc.y = acc.y * sc + w * vv.y;
        acc.z = acc.z * sc + w * vv.z;
        acc.w = acc.w * sc + w * vv.w;
        m = mnew;
    }

    const int pidx = (b * NH + head) * NCHUNK + chunk;
    if (lig == 0) { pm[pidx] = m; pl[pidx] = l; }
    *(float4*)(pctx + (size_t)pidx * HD + lig * 4) = acc;
}

// -------- kernel 3: reduce chunk partials per (b,h) --------
__global__ __launch_bounds__(256) void reduce_kernel(const float* __restrict__ pm,
                                                     const float* __restrict__ pl,
                                                     const float* __restrict__ pctx,
                                                     float* __restrict__ ctxout) {
    const int gw = (blockIdx.x * blockDim.x + threadIdx.x) >> 6;  // (b*NH+head)
    const int lane = threadIdx.x & 63;
    if (gw >= BATCH * NH) return;
    float mg = -3.0e38f;
    for (int c = 0; c < NCHUNK; ++c) mg = fmaxf(mg, pm[gw * NCHUNK + c]);
    float lacc = 0.f, cacc = 0.f;
    for (int c = 0; c < NCHUNK; ++c) {
        const float e = __expf(pm[gw * NCHUNK + c] - mg);
        lacc = fmaf(pl[gw * NCHUNK + c], e, lacc);
        cacc = fmaf(pctx[(size_t)(gw * NCHUNK + c) * HD + lane], e, cacc);
    }
    ctxout[gw * HD + lane] = cacc / lacc;
}

// -------- kernel 4: out = ctx @ c_proj_w + c_proj_b --------
__global__ __launch_bounds__(256) void proj_kernel(const float* __restrict__ ctx,
                                                   const float* __restrict__ W,
                                                   const float* __restrict__ bias,
                                                   float* __restrict__ out) {
    int b = blockIdx.y;
    int j = blockIdx.x * 256 + threadIdx.x;
    __shared__ float h[E_DIM];
    for (int i = threadIdx.x; i < E_DIM; i += 256) h[i] = ctx[b * E_DIM + i];
    __syncthreads();
    float acc = bias[j];
    for (int i = 0; i < E_DIM; ++i) acc = fmaf(h[i], W[(size_t)i * E_DIM + j], acc);
    out[b * E_DIM + j] = acc;
}

extern "C" void kernel_launch(void* const* d_in, const int* in_sizes, int n_in,
                              void* d_out, int out_size, void* d_ws, size_t ws_size,
                              hipStream_t stream) {
    const float* hs      = (const float*)d_in[0];
    const float* kcache  = (const float*)d_in[1];
    const float* vcache  = (const float*)d_in[2];
    const int*   mask    = (const int*)d_in[3];
    const float* attn_w  = (const float*)d_in[4];
    const float* attn_b  = (const float*)d_in[5];
    const float* proj_w  = (const float*)d_in[6];
    const float* proj_b  = (const float*)d_in[7];
    const float* bias0   = (const float*)d_in[8];  // row 0 of attn_bias

    float* out0 = (float*)d_out;                         // 32*1024
    float* newk = out0 + (size_t)BATCH * E_DIM;          // 32*4096*1024
    float* newv = newk + (size_t)BATCH * SEQ * E_DIM;

    float* ws = (float*)d_ws;
    float* qkv     = ws;                     // 98304
    float* ctxbuf  = qkv + 98304;            // 32768
    float* pm      = ctxbuf + 32768;         // 16384
    float* pl      = pm + 16384;             // 16384
    float* pctx    = pl + 16384;             // 1048576
    int*   lastbuf = (int*)(pctx + 1048576); // 32

    last_kernel<<<dim3(BATCH), dim3(256), 0, stream>>>(mask, lastbuf);
    qkv_kernel<<<dim3(12, BATCH), dim3(256), 0, stream>>>(hs, attn_w, attn_b, qkv);
    attn_partial_kernel<<<dim3(NCHUNK, BATCH), dim3(256), 0, stream>>>(
        kcache, vcache, mask, bias0, qkv, lastbuf, newk, newv, pm, pl, pctx);
    reduce_kernel<<<dim3((BATCH * NH * 64 + 255) / 256), dim3(256), 0, stream>>>(
        pm, pl, pctx, ctxbuf);
    proj_kernel<<<dim3(4, BATCH), dim3(256), 0, stream>>>(ctxbuf, proj_w, proj_b, out0);
}